// Round 9
// baseline (6617.809 us; speedup 1.0000x reference)
//
#include <hip/hip_runtime.h>

// CRITICAL: bit-exact replication of the numpy fp32 oracle requires NO FMA
// contraction (hipcc default -ffp-contract=fast-honor-pragmas would fuse).
#pragma clang fp contract(off)

#define D4    83521      // 17^4 entries per LUT (per channel)
#define HW    262144     // 512*512
#define NPIX  2097152    // 8*512*512
#define NBIN  4096       // bins = (i0,i1,i2), i3 excluded

// ---------------------------------------------------------------------------
// The verified round-6 stage body, verbatim (bit-exact vs the numpy oracle).
// Used by every tier — single definition to avoid transcription drift.
__device__ __forceinline__ float4 stage_interp(float x0, float x1, float x2,
                                               float x3,
                                               const float4* __restrict__ lut) {
#pragma clang fp contract(off)
    x0 = fminf(fmaxf(x0, 0.f), 1.f);
    x1 = fminf(fmaxf(x1, 0.f), 1.f);
    x2 = fminf(fmaxf(x2, 0.f), 1.f);
    x3 = fminf(fmaxf(x3, 0.f), 1.f);

    float xs0 = x0 * 16.f;
    float xs1 = x1 * 16.f;
    float xs2 = x2 * 16.f;
    float xs3 = x3 * 16.f;
    int i0 = (int)xs0; i0 = i0 > 15 ? 15 : i0;
    int i1 = (int)xs1; i1 = i1 > 15 ? 15 : i1;
    int i2 = (int)xs2; i2 = i2 > 15 ? 15 : i2;
    int i3 = (int)xs3; i3 = i3 > 15 ? 15 : i3;
    float f0 = xs0 - (float)i0;   // mul-then-sub, contraction OFF
    float f1 = xs1 - (float)i1;
    float f2 = xs2 - (float)i2;
    float f3 = xs3 - (float)i3;
    float g0 = 1.f - f0;
    float g1 = 1.f - f1;
    float g2 = 1.f - f2;
    float g3 = 1.f - f3;

    // w01[b1*2+b0] = (b0?f0:g0)*(b1?f1:g1)
    float w01[4] = { g0 * g1, f0 * g1, g0 * f1, f0 * f1 };
    int off = i0 * 4913 + i1 * 289 + i2 * 17 + i3;

    float a0 = 0.f, a1 = 0.f, a2 = 0.f, a3 = 0.f;
#pragma unroll
    for (int hi = 0; hi < 2; ++hi) {
        float w3 = hi ? f3 : g3;
#pragma unroll
        for (int c = 0; c < 8; ++c) {
            int d = (c & 1) * 4913 + ((c >> 1) & 1) * 289 + (c >> 2) * 17 + hi;
            float4 v = lut[off + d];
            float w012 = w01[c & 3] * ((c >> 2) ? f2 : g2);
            float w    = w012 * w3;
            if (hi == 0 && c == 0) {
                a0 = v.x * w; a1 = v.y * w; a2 = v.z * w; a3 = v.w * w;
            } else {
                a0 = a0 + v.x * w; a1 = a1 + v.y * w;
                a2 = a2 + v.z * w; a3 = a3 + v.w * w;
            }
        }
    }
    return make_float4(a0, a1, a2, a3);
}

// Bin key = (i0,i1,i2) via the EXACT index computation the interp uses.
__device__ __forceinline__ int cell_of(float x0, float x1, float x2) {
    x0 = fminf(fmaxf(x0, 0.f), 1.f);
    x1 = fminf(fmaxf(x1, 0.f), 1.f);
    x2 = fminf(fmaxf(x2, 0.f), 1.f);
    float xs0 = x0 * 16.f;
    float xs1 = x1 * 16.f;
    float xs2 = x2 * 16.f;
    int i0 = (int)xs0; i0 = i0 > 15 ? 15 : i0;
    int i1 = (int)xs1; i1 = i1 > 15 ? 15 : i1;
    int i2 = (int)xs2; i2 = i2 > 15 ? 15 : i2;
    return (i0 * 16 + i1) * 16 + i2;
}

// ---------- LUT packing (round-6, proven) -----------------------------------
__global__ __launch_bounds__(256) void pack_kernel(const float* __restrict__ src,
                                                   int n_ch,
                                                   float4* __restrict__ dst) {
    int e = blockIdx.x * 256 + threadIdx.x;
    if (e >= D4) return;
    float4 v;
    v.x = src[e];
    v.y = src[D4 + e];
    v.z = src[2 * D4 + e];
    v.w = (n_ch == 4) ? src[3 * D4 + e] : 0.f;
    dst[e] = v;
}

// ---------- binned pipeline kernels -----------------------------------------
__global__ __launch_bounds__(256) void k_zero(unsigned* __restrict__ hist) {
    int i = blockIdx.x * 256 + threadIdx.x;
    if (i < NBIN) hist[i] = 0u;
}

// Natural-order init: store raw coords + pid, histogram stage-0 cells.
__global__ __launch_bounds__(256) void k_init(const float* __restrict__ vi,
                                              const float* __restrict__ ir,
                                              float4* __restrict__ coordsA,
                                              unsigned* __restrict__ pidA,
                                              unsigned* __restrict__ hist) {
    int p = blockIdx.x * 256 + threadIdx.x;
    if (p >= NPIX) return;
    int b  = p >> 18;
    int hw = p & (HW - 1);
    int vbase = (b * 3) << 18;
    float x0 = vi[vbase + hw];
    float x1 = vi[vbase + HW + hw];
    float x2 = vi[vbase + 2 * HW + hw];
    float x3 = ir[p];
    coordsA[p] = make_float4(x0, x1, x2, x3);
    pidA[p] = (unsigned)p;
    atomicAdd(&hist[cell_of(x0, x1, x2)], 1u);
}

// Single-block exclusive scan of hist -> cursor; zeroes hist for reuse.
__global__ __launch_bounds__(256) void k_scan(unsigned* __restrict__ hist,
                                              unsigned* __restrict__ cursor) {
    __shared__ unsigned part[256];
    int t = threadIdx.x;                 // 16 contiguous bins per thread
    unsigned loc[16];
    unsigned sum = 0;
#pragma unroll
    for (int k = 0; k < 16; ++k) { loc[k] = hist[t * 16 + k]; sum += loc[k]; }
    part[t] = sum;
    __syncthreads();
    if (t == 0) {
        unsigned run = 0;
        for (int i = 0; i < 256; ++i) { unsigned v = part[i]; part[i] = run; run += v; }
    }
    __syncthreads();
    unsigned off = part[t];
#pragma unroll
    for (int k = 0; k < 16; ++k) {
        cursor[t * 16 + k] = off;
        off += loc[k];
        hist[t * 16 + k] = 0u;           // ready for next stage's histogram
    }
}

// Counting-sort scatter: A (stage order) -> B (bin-sorted order).
__global__ __launch_bounds__(256) void k_scatter(const float4* __restrict__ coordsA,
                                                 const unsigned* __restrict__ pidA,
                                                 unsigned* __restrict__ cursor,
                                                 float4* __restrict__ coordsB,
                                                 unsigned* __restrict__ pidB) {
    int j = blockIdx.x * 256 + threadIdx.x;
    if (j >= NPIX) return;
    float4 c = coordsA[j];
    unsigned pid = pidA[j];
    int cell = cell_of(c.x, c.y, c.z);
    unsigned slot = atomicAdd(&cursor[cell], 1u);
    coordsB[slot] = c;
    pidB[slot] = pid;
}

// Interp one stage on sorted pixels (coalesced LUT access within a wave);
// also histogram the NEXT stage's cells.
__global__ __launch_bounds__(256) void k_interp(const float4* __restrict__ coordsB,
                                                const unsigned* __restrict__ pidB,
                                                const float4* __restrict__ lut,
                                                float4* __restrict__ coordsA,
                                                unsigned* __restrict__ pidA,
                                                unsigned* __restrict__ hist) {
#pragma clang fp contract(off)
    int j = blockIdx.x * 256 + threadIdx.x;
    if (j >= NPIX) return;
    float4 c = coordsB[j];
    unsigned pid = pidB[j];
    float4 a = stage_interp(c.x, c.y, c.z, c.w, lut);
    coordsA[j] = a;
    pidA[j] = pid;
    atomicAdd(&hist[cell_of(a.x, a.y, a.z)], 1u);
}

// Final stage: interp + scatter 3 channels to natural-order output.
__global__ __launch_bounds__(256) void k_interp_last(const float4* __restrict__ coordsB,
                                                     const unsigned* __restrict__ pidB,
                                                     const float4* __restrict__ lut,
                                                     float* __restrict__ out) {
#pragma clang fp contract(off)
    int j = blockIdx.x * 256 + threadIdx.x;
    if (j >= NPIX) return;
    float4 c = coordsB[j];
    unsigned pid = pidB[j];
    float4 a = stage_interp(c.x, c.y, c.z, c.w, lut);
    int b  = (int)(pid >> 18);
    int hw = (int)(pid & (HW - 1));
    int vbase = (b * 3) << 18;
    out[vbase + hw]          = a.x;
    out[vbase + HW + hw]     = a.y;
    out[vbase + 2 * HW + hw] = a.z;
}

// ---------- middle tier: round-6 fused kernel (known-passing, 757 us) -------
__global__ __launch_bounds__(256) void fused_kernel(const float* __restrict__ vi,
                                                    const float* __restrict__ ir,
                                                    const float4* __restrict__ luts,
                                                    float* __restrict__ out) {
#pragma clang fp contract(off)
    int p = blockIdx.x * 256 + threadIdx.x;
    if (p >= NPIX) return;
    int b  = p >> 18;
    int hw = p & (HW - 1);
    int vbase = (b * 3) << 18;

    float x0 = vi[vbase + hw];
    float x1 = vi[vbase + HW + hw];
    float x2 = vi[vbase + 2 * HW + hw];
    float x3 = ir[p];

    for (int s = 0; s < 6; ++s) {
        float4 a = stage_interp(x0, x1, x2, x3, luts + (size_t)s * D4);
        x0 = a.x; x1 = a.y; x2 = a.z; x3 = a.w;
    }
    out[vbase + hw]          = x0;
    out[vbase + HW + hw]     = x1;
    out[vbase + 2 * HW + hw] = x2;
}

// ---------- raw fallback (no workspace) -------------------------------------
__global__ __launch_bounds__(256) void fused_fallback(const float* __restrict__ vi,
                                                      const float* __restrict__ ir,
                                                      const float* __restrict__ l8,
                                                      const float* __restrict__ l00,
                                                      const float* __restrict__ l01,
                                                      const float* __restrict__ l02,
                                                      const float* __restrict__ l03,
                                                      const float* __restrict__ lpgf,
                                                      float* __restrict__ out) {
#pragma clang fp contract(off)
    int p = blockIdx.x * 256 + threadIdx.x;
    if (p >= NPIX) return;
    int b  = p >> 18;
    int hw = p & (HW - 1);
    int vbase = (b * 3) << 18;

    const float* ptrs[6] = { l8, l00, l01, l02, l03, lpgf };

    float x0 = vi[vbase + hw];
    float x1 = vi[vbase + HW + hw];
    float x2 = vi[vbase + 2 * HW + hw];
    float x3 = ir[p];

    for (int s = 0; s < 6; ++s) {
        const float* __restrict__ L = ptrs[s];
        int n_ch = (s == 5) ? 3 : 4;
        x0 = fminf(fmaxf(x0, 0.f), 1.f);
        x1 = fminf(fmaxf(x1, 0.f), 1.f);
        x2 = fminf(fmaxf(x2, 0.f), 1.f);
        x3 = fminf(fmaxf(x3, 0.f), 1.f);
        float xs0 = x0 * 16.f;
        float xs1 = x1 * 16.f;
        float xs2 = x2 * 16.f;
        float xs3 = x3 * 16.f;
        int i0 = (int)xs0; i0 = i0 > 15 ? 15 : i0;
        int i1 = (int)xs1; i1 = i1 > 15 ? 15 : i1;
        int i2 = (int)xs2; i2 = i2 > 15 ? 15 : i2;
        int i3 = (int)xs3; i3 = i3 > 15 ? 15 : i3;
        float f0 = xs0 - (float)i0;
        float f1 = xs1 - (float)i1;
        float f2 = xs2 - (float)i2;
        float f3 = xs3 - (float)i3;
        float g0 = 1.f - f0;
        float g1 = 1.f - f1;
        float g2 = 1.f - f2;
        float g3 = 1.f - f3;
        float w01[4] = { g0 * g1, f0 * g1, g0 * f1, f0 * f1 };
        int off = i0 * 4913 + i1 * 289 + i2 * 17 + i3;
        float a0 = 0.f, a1 = 0.f, a2 = 0.f, a3 = 0.f;
        for (int cr = 0; cr < 16; ++cr) {
            int hi = cr >> 3, c = cr & 7;
            int idx = off + (c & 1) * 4913 + ((c >> 1) & 1) * 289 + (c >> 2) * 17 + hi;
            float w012 = w01[c & 3] * ((c >> 2) ? f2 : g2);
            float w    = w012 * (hi ? f3 : g3);
            float v0 = L[idx];
            float v1 = L[D4 + idx];
            float v2 = L[2 * D4 + idx];
            float v3 = (n_ch == 4) ? L[3 * D4 + idx] : 0.f;
            if (cr == 0) {
                a0 = v0 * w; a1 = v1 * w; a2 = v2 * w; a3 = v3 * w;
            } else {
                a0 = a0 + v0 * w; a1 = a1 + v1 * w;
                a2 = a2 + v2 * w; a3 = a3 + v3 * w;
            }
        }
        x0 = a0; x1 = a1; x2 = a2; x3 = a3;
    }

    out[vbase + hw]          = x0;
    out[vbase + HW + hw]     = x1;
    out[vbase + 2 * HW + hw] = x2;
}

extern "C" void kernel_launch(void* const* d_in, const int* in_sizes, int n_in,
                              void* d_out, int out_size, void* d_ws, size_t ws_size,
                              hipStream_t stream) {
    const float* vi = (const float*)d_in[0];
    const float* ir = (const float*)d_in[1];
    const float* raw[6] = {
        (const float*)d_in[2], (const float*)d_in[3],
        (const float*)d_in[4], (const float*)d_in[5],
        (const float*)d_in[6], (const float*)d_in[7]
    };
    float* out = (float*)d_out;

    // ws layout (binned path), 256-aligned blocks:
    const size_t LUT_OFF  = 0;
    const size_t LUT_SZ   = (size_t)6 * D4 * 16;          // 8,018,016
    const size_t HIST_OFF = 8018176;
    const size_t CURS_OFF = HIST_OFF + 16640;             // 4096*4 padded
    const size_t CA_OFF   = CURS_OFF + 16640;
    const size_t PA_OFF   = CA_OFF + (size_t)NPIX * 16;
    const size_t CB_OFF   = PA_OFF + (size_t)NPIX * 4;
    const size_t PB_OFF   = CB_OFF + (size_t)NPIX * 16;
    const size_t NEED     = PB_OFF + (size_t)NPIX * 4;    // ~92.0 MB
    const size_t NEED_LIN = LUT_SZ;                       // ~8.0 MB

    if (ws_size >= NEED) {
        char* ws = (char*)d_ws;
        float4*   luts    = (float4*)(ws + LUT_OFF);
        unsigned* hist    = (unsigned*)(ws + HIST_OFF);
        unsigned* cursor  = (unsigned*)(ws + CURS_OFF);
        float4*   coordsA = (float4*)(ws + CA_OFF);
        unsigned* pidA    = (unsigned*)(ws + PA_OFF);
        float4*   coordsB = (float4*)(ws + CB_OFF);
        unsigned* pidB    = (unsigned*)(ws + PB_OFF);

        int pack_blocks = (D4 + 255) / 256;
        for (int s = 0; s < 6; ++s) {
            pack_kernel<<<pack_blocks, 256, 0, stream>>>(raw[s], (s == 5) ? 3 : 4,
                                                         luts + (size_t)s * D4);
        }
        k_zero<<<NBIN / 256, 256, 0, stream>>>(hist);
        k_init<<<NPIX / 256, 256, 0, stream>>>(vi, ir, coordsA, pidA, hist);
        for (int s = 0; s < 6; ++s) {
            k_scan<<<1, 256, 0, stream>>>(hist, cursor);
            k_scatter<<<NPIX / 256, 256, 0, stream>>>(coordsA, pidA, cursor,
                                                      coordsB, pidB);
            if (s < 5) {
                k_interp<<<NPIX / 256, 256, 0, stream>>>(coordsB, pidB,
                                                         luts + (size_t)s * D4,
                                                         coordsA, pidA, hist);
            } else {
                k_interp_last<<<NPIX / 256, 256, 0, stream>>>(coordsB, pidB,
                                                              luts + (size_t)5 * D4,
                                                              out);
            }
        }
    } else if (ws_size >= NEED_LIN) {
        float4* packed = (float4*)d_ws;
        int pack_blocks = (D4 + 255) / 256;
        for (int s = 0; s < 6; ++s) {
            pack_kernel<<<pack_blocks, 256, 0, stream>>>(raw[s], (s == 5) ? 3 : 4,
                                                         packed + (size_t)s * D4);
        }
        fused_kernel<<<NPIX / 256, 256, 0, stream>>>(vi, ir, packed, out);
    } else {
        fused_fallback<<<NPIX / 256, 256, 0, stream>>>(vi, ir, raw[0], raw[1], raw[2],
                                                       raw[3], raw[4], raw[5], out);
    }
}

// Round 10
// 721.278 us; speedup vs baseline: 9.1751x; 9.1751x over previous
//
#include <hip/hip_runtime.h>

// CRITICAL: bit-exact replication of the numpy fp32 oracle requires NO FMA
// contraction (hipcc default -ffp-contract=fast-honor-pragmas would fuse).
#pragma clang fp contract(off)

#define D4    83521      // 17^4 entries per LUT (per channel)
#define HW    262144     // 512*512
#define NPIX  2097152    // 8*512*512

// ---------- LUT packing: [C][17^4] -> [17^4][4ch] float4 (proven) -----------
__global__ __launch_bounds__(256) void pack_kernel(const float* __restrict__ src,
                                                   int n_ch,
                                                   float4* __restrict__ dst) {
    int e = blockIdx.x * 256 + threadIdx.x;
    if (e >= D4) return;
    float4 v;
    v.x = src[e];
    v.y = src[D4 + e];
    v.z = src[2 * D4 + e];
    v.w = (n_ch == 4) ? src[3 * D4 + e] : 0.f;
    dst[e] = v;
}

// Fused 6-stage chain, forced-MLP variant.
// Identical arithmetic to the verified round-6 kernel (fp32, no contraction,
// weights ((w0*w1)*w2)*w3, corners 0..15 strictly sequential). The ONLY change:
// all 16 LUT gathers are issued first and pinned before the math with
// sched_barrier(0) so the scheduler cannot sink them into the accumulation
// chain (round 6/8 builds kept VGPR=32 and only ~3 gathers in flight ->
// possibly per-wave latency-bound). Loads carry no numeric effect, so
// bit-exactness is preserved by construction.
__global__ __launch_bounds__(256) void fused_mlp(const float* __restrict__ vi,
                                                 const float* __restrict__ ir,
                                                 const float4* __restrict__ luts,
                                                 float* __restrict__ out) {
#pragma clang fp contract(off)
    int p = blockIdx.x * 256 + threadIdx.x;
    if (p >= NPIX) return;
    int b  = p >> 18;             // HW = 2^18
    int hw = p & (HW - 1);
    int vbase = (b * 3) << 18;

    float x0 = vi[vbase + hw];
    float x1 = vi[vbase + HW + hw];
    float x2 = vi[vbase + 2 * HW + hw];
    float x3 = ir[p];

    for (int s = 0; s < 6; ++s) {
        const float4* __restrict__ lut = luts + (size_t)s * D4;
        x0 = fminf(fmaxf(x0, 0.f), 1.f);
        x1 = fminf(fmaxf(x1, 0.f), 1.f);
        x2 = fminf(fmaxf(x2, 0.f), 1.f);
        x3 = fminf(fmaxf(x3, 0.f), 1.f);

        float xs0 = x0 * 16.f;
        float xs1 = x1 * 16.f;
        float xs2 = x2 * 16.f;
        float xs3 = x3 * 16.f;
        int i0 = (int)xs0; i0 = i0 > 15 ? 15 : i0;
        int i1 = (int)xs1; i1 = i1 > 15 ? 15 : i1;
        int i2 = (int)xs2; i2 = i2 > 15 ? 15 : i2;
        int i3 = (int)xs3; i3 = i3 > 15 ? 15 : i3;
        float f0 = xs0 - (float)i0;   // mul-then-sub, contraction OFF
        float f1 = xs1 - (float)i1;
        float f2 = xs2 - (float)i2;
        float f3 = xs3 - (float)i3;
        float g0 = 1.f - f0;
        float g1 = 1.f - f1;
        float g2 = 1.f - f2;
        float g3 = 1.f - f3;

        // w01[b1*2+b0] = (b0?f0:g0)*(b1?f1:g1)
        float w01[4] = { g0 * g1, f0 * g1, g0 * f1, f0 * f1 };
        int off = i0 * 4913 + i1 * 289 + i2 * 17 + i3;

        // ---- phase 1: issue ALL 16 gathers ----
        float4 v[16];
#pragma unroll
        for (int hi = 0; hi < 2; ++hi) {
#pragma unroll
            for (int c = 0; c < 8; ++c) {
                int d = (c & 1) * 4913 + ((c >> 1) & 1) * 289 + (c >> 2) * 17 + hi;
                v[hi * 8 + c] = lut[off + d];
            }
        }
        // Pin the loads: nothing may be scheduled across this point.
        __builtin_amdgcn_sched_barrier(0);

        // ---- phase 2: exact round-6 sequential accumulation ----
        float a0 = 0.f, a1 = 0.f, a2 = 0.f, a3 = 0.f;
#pragma unroll
        for (int hi = 0; hi < 2; ++hi) {
            float w3 = hi ? f3 : g3;
#pragma unroll
            for (int c = 0; c < 8; ++c) {
                float4 vv = v[hi * 8 + c];
                float w012 = w01[c & 3] * ((c >> 2) ? f2 : g2);
                float w    = w012 * w3;
                if (hi == 0 && c == 0) {
                    a0 = vv.x * w; a1 = vv.y * w; a2 = vv.z * w; a3 = vv.w * w;
                } else {
                    a0 = a0 + vv.x * w; a1 = a1 + vv.y * w;
                    a2 = a2 + vv.z * w; a3 = a3 + vv.w * w;
                }
            }
        }
        x0 = a0; x1 = a1; x2 = a2; x3 = a3;
    }

    out[vbase + hw]          = x0;
    out[vbase + HW + hw]     = x1;
    out[vbase + 2 * HW + hw] = x2;
}

// ---------- raw fallback (no workspace) -------------------------------------
__global__ __launch_bounds__(256) void fused_fallback(const float* __restrict__ vi,
                                                      const float* __restrict__ ir,
                                                      const float* __restrict__ l8,
                                                      const float* __restrict__ l00,
                                                      const float* __restrict__ l01,
                                                      const float* __restrict__ l02,
                                                      const float* __restrict__ l03,
                                                      const float* __restrict__ lpgf,
                                                      float* __restrict__ out) {
#pragma clang fp contract(off)
    int p = blockIdx.x * 256 + threadIdx.x;
    if (p >= NPIX) return;
    int b  = p >> 18;
    int hw = p & (HW - 1);
    int vbase = (b * 3) << 18;

    const float* ptrs[6] = { l8, l00, l01, l02, l03, lpgf };

    float x0 = vi[vbase + hw];
    float x1 = vi[vbase + HW + hw];
    float x2 = vi[vbase + 2 * HW + hw];
    float x3 = ir[p];

    for (int s = 0; s < 6; ++s) {
        const float* __restrict__ L = ptrs[s];
        int n_ch = (s == 5) ? 3 : 4;
        x0 = fminf(fmaxf(x0, 0.f), 1.f);
        x1 = fminf(fmaxf(x1, 0.f), 1.f);
        x2 = fminf(fmaxf(x2, 0.f), 1.f);
        x3 = fminf(fmaxf(x3, 0.f), 1.f);
        float xs0 = x0 * 16.f;
        float xs1 = x1 * 16.f;
        float xs2 = x2 * 16.f;
        float xs3 = x3 * 16.f;
        int i0 = (int)xs0; i0 = i0 > 15 ? 15 : i0;
        int i1 = (int)xs1; i1 = i1 > 15 ? 15 : i1;
        int i2 = (int)xs2; i2 = i2 > 15 ? 15 : i2;
        int i3 = (int)xs3; i3 = i3 > 15 ? 15 : i3;
        float f0 = xs0 - (float)i0;
        float f1 = xs1 - (float)i1;
        float f2 = xs2 - (float)i2;
        float f3 = xs3 - (float)i3;
        float g0 = 1.f - f0;
        float g1 = 1.f - f1;
        float g2 = 1.f - f2;
        float g3 = 1.f - f3;
        float w01[4] = { g0 * g1, f0 * g1, g0 * f1, f0 * f1 };
        int off = i0 * 4913 + i1 * 289 + i2 * 17 + i3;
        float a0 = 0.f, a1 = 0.f, a2 = 0.f, a3 = 0.f;
        for (int cr = 0; cr < 16; ++cr) {
            int hi = cr >> 3, c = cr & 7;
            int idx = off + (c & 1) * 4913 + ((c >> 1) & 1) * 289 + (c >> 2) * 17 + hi;
            float w012 = w01[c & 3] * ((c >> 2) ? f2 : g2);
            float w    = w012 * (hi ? f3 : g3);
            float v0 = L[idx];
            float v1 = L[D4 + idx];
            float v2 = L[2 * D4 + idx];
            float v3 = (n_ch == 4) ? L[3 * D4 + idx] : 0.f;
            if (cr == 0) {
                a0 = v0 * w; a1 = v1 * w; a2 = v2 * w; a3 = v3 * w;
            } else {
                a0 = a0 + v0 * w; a1 = a1 + v1 * w;
                a2 = a2 + v2 * w; a3 = a3 + v3 * w;
            }
        }
        x0 = a0; x1 = a1; x2 = a2; x3 = a3;
    }

    out[vbase + hw]          = x0;
    out[vbase + HW + hw]     = x1;
    out[vbase + 2 * HW + hw] = x2;
}

extern "C" void kernel_launch(void* const* d_in, const int* in_sizes, int n_in,
                              void* d_out, int out_size, void* d_ws, size_t ws_size,
                              hipStream_t stream) {
    const float* vi = (const float*)d_in[0];
    const float* ir = (const float*)d_in[1];
    const float* raw[6] = {
        (const float*)d_in[2], (const float*)d_in[3],
        (const float*)d_in[4], (const float*)d_in[5],
        (const float*)d_in[6], (const float*)d_in[7]
    };
    float* out = (float*)d_out;

    size_t need_lin = (size_t)6 * D4 * sizeof(float4);   // ~8.0 MB packed LUTs
    if (ws_size >= need_lin) {
        float4* packed = (float4*)d_ws;
        int pack_blocks = (D4 + 255) / 256;
        for (int s = 0; s < 6; ++s) {
            pack_kernel<<<pack_blocks, 256, 0, stream>>>(raw[s], (s == 5) ? 3 : 4,
                                                         packed + (size_t)s * D4);
        }
        fused_mlp<<<NPIX / 256, 256, 0, stream>>>(vi, ir, packed, out);
    } else {
        fused_fallback<<<NPIX / 256, 256, 0, stream>>>(vi, ir, raw[0], raw[1], raw[2],
                                                       raw[3], raw[4], raw[5], out);
    }
}

// Round 11
// 703.155 us; speedup vs baseline: 9.4116x; 1.0258x over previous
//
#include <hip/hip_runtime.h>

// CRITICAL: bit-exact replication of the numpy fp32 oracle requires NO FMA
// contraction (hipcc default -ffp-contract=fast-honor-pragmas would fuse).
#pragma clang fp contract(off)

#define D4    83521      // 17^4 entries per LUT (per channel)
#define HW    262144     // 512*512
#define NPIX  2097152    // 8*512*512
#define QREC  73984      // 17*17*16*16 quad records per LUT (64 B each)

// ---------- quad packing: one 64 B record = 2x2 (i2,i3) corner block --------
// Record r = ((i0*17 + i1)*16 + i2)*16 + i3 (i2,i3 in [0,16)); slot g holds
// channels of corner (i2+(g&1), i3+(g>>1)). Verified bit-exact in round 7.
__global__ __launch_bounds__(256) void pack_quad(const float* __restrict__ src,
                                                 int n_ch,
                                                 float4* __restrict__ dst) {
    int e = blockIdx.x * 256 + threadIdx.x;
    if (e >= QREC) return;
    int i3 = e & 15;
    int i2 = (e >> 4) & 15;
    int t  = e >> 8;              // i0*17 + i1
    int i0 = t / 17;
    int i1 = t - i0 * 17;
    int base = i0 * 4913 + i1 * 289 + i2 * 17 + i3;
    float4* rec = dst + (size_t)e * 4;
#pragma unroll
    for (int g = 0; g < 4; ++g) {
        int o = base + (g & 1) * 17 + (g >> 1);
        float4 v;
        v.x = src[o];
        v.y = src[D4 + o];
        v.z = src[2 * D4 + o];
        v.w = (n_ch == 4) ? src[3 * D4 + o] : 0.f;
        rec[g] = v;
    }
}

// One stage via quad records, forced MLP. Arithmetic is the verified round-6
// sequence verbatim (corner c_ref = b3*8 + b2*4 + b1*2 + b0, sequential;
// weight ((w01)*w2)*w3; fp32, no contraction). Record (i0+b0,i1+b1),
// slot b2+2*b3 — the round-7 mapping that passed absmax 0.0.
__device__ __forceinline__ float4 stage_quad(float x0, float x1, float x2,
                                             float x3,
                                             const float4* __restrict__ lut) {
#pragma clang fp contract(off)
    x0 = fminf(fmaxf(x0, 0.f), 1.f);
    x1 = fminf(fmaxf(x1, 0.f), 1.f);
    x2 = fminf(fmaxf(x2, 0.f), 1.f);
    x3 = fminf(fmaxf(x3, 0.f), 1.f);

    float xs0 = x0 * 16.f;
    float xs1 = x1 * 16.f;
    float xs2 = x2 * 16.f;
    float xs3 = x3 * 16.f;
    int i0 = (int)xs0; i0 = i0 > 15 ? 15 : i0;
    int i1 = (int)xs1; i1 = i1 > 15 ? 15 : i1;
    int i2 = (int)xs2; i2 = i2 > 15 ? 15 : i2;
    int i3 = (int)xs3; i3 = i3 > 15 ? 15 : i3;
    float f0 = xs0 - (float)i0;   // mul-then-sub, contraction OFF
    float f1 = xs1 - (float)i1;
    float f2 = xs2 - (float)i2;
    float f3 = xs3 - (float)i3;
    float g0 = 1.f - f0;
    float g1 = 1.f - f1;
    float g2 = 1.f - f2;
    float g3 = 1.f - f3;

    // w01[b1*2+b0] = (b0?f0:g0)*(b1?f1:g1)
    float w01[4] = { g0 * g1, f0 * g1, g0 * f1, f0 * f1 };

    int r00 = ((i0 * 17 + i1) * 16 + i2) * 16 + i3;
    const float4* q00 = lut + (size_t)r00 * 4;
    const float4* q10 = q00 + (size_t)4352 * 4;   // +i0 record stride 17*16*16
    const float4* q01 = q00 + (size_t)256 * 4;    // +i1 record stride 16*16
    const float4* q11 = q00 + (size_t)4608 * 4;

    // ---- phase 1: issue all 16 loads (4 records x 4 slots) ----
    float4 v[16];                 // v[rec*4 + slot]; rec = b0 + 2*b1
#pragma unroll
    for (int g = 0; g < 4; ++g) {
        v[0 * 4 + g] = q00[g];
        v[1 * 4 + g] = q10[g];
        v[2 * 4 + g] = q01[g];
        v[3 * 4 + g] = q11[g];
    }
    __builtin_amdgcn_sched_barrier(0);   // pin loads before the math

    // ---- phase 2: exact round-6 sequential accumulation ----
    float a0 = 0.f, a1 = 0.f, a2 = 0.f, a3 = 0.f;
#pragma unroll
    for (int hi = 0; hi < 2; ++hi) {     // b3
        float w3 = hi ? f3 : g3;
#pragma unroll
        for (int c = 0; c < 8; ++c) {    // b0=c&1, b1=(c>>1)&1, b2=c>>2
            int rec  = c & 3;            // b0 + 2*b1
            int slot = (c >> 2) + 2 * hi;
            float4 vv = v[rec * 4 + slot];
            float w012 = w01[c & 3] * ((c >> 2) ? f2 : g2);
            float w    = w012 * w3;
            if (hi == 0 && c == 0) {
                a0 = vv.x * w; a1 = vv.y * w; a2 = vv.z * w; a3 = vv.w * w;
            } else {
                a0 = a0 + vv.x * w; a1 = a1 + vv.y * w;
                a2 = a2 + vv.z * w; a3 = a3 + vv.w * w;
            }
        }
    }
    return make_float4(a0, a1, a2, a3);
}

// Stage 0: read inputs, interp, write coords.
__global__ __launch_bounds__(256) void k_stage_first(const float* __restrict__ vi,
                                                     const float* __restrict__ ir,
                                                     const float4* __restrict__ lut,
                                                     float4* __restrict__ coords) {
#pragma clang fp contract(off)
    int p = blockIdx.x * 256 + threadIdx.x;
    if (p >= NPIX) return;
    int b  = p >> 18;
    int hw = p & (HW - 1);
    int vbase = (b * 3) << 18;
    float x0 = vi[vbase + hw];
    float x1 = vi[vbase + HW + hw];
    float x2 = vi[vbase + 2 * HW + hw];
    float x3 = ir[p];
    coords[p] = stage_quad(x0, x1, x2, x3, lut);
}

// Stages 1..4: coords -> coords (in place).
__global__ __launch_bounds__(256) void k_stage_mid(float4* __restrict__ coords,
                                                   const float4* __restrict__ lut) {
#pragma clang fp contract(off)
    int p = blockIdx.x * 256 + threadIdx.x;
    if (p >= NPIX) return;
    float4 c = coords[p];
    coords[p] = stage_quad(c.x, c.y, c.z, c.w, lut);
}

// Stage 5: coords -> out (natural order).
__global__ __launch_bounds__(256) void k_stage_last(const float4* __restrict__ coords,
                                                    const float4* __restrict__ lut,
                                                    float* __restrict__ out) {
#pragma clang fp contract(off)
    int p = blockIdx.x * 256 + threadIdx.x;
    if (p >= NPIX) return;
    float4 c = coords[p];
    float4 a = stage_quad(c.x, c.y, c.z, c.w, lut);
    int b  = p >> 18;
    int hw = p & (HW - 1);
    int vbase = (b * 3) << 18;
    out[vbase + hw]          = a.x;
    out[vbase + HW + hw]     = a.y;
    out[vbase + 2 * HW + hw] = a.z;
}

// ---------- middle tier: round-10 fused kernel (proven, 653 us) -------------
__global__ __launch_bounds__(256) void pack_kernel(const float* __restrict__ src,
                                                   int n_ch,
                                                   float4* __restrict__ dst) {
    int e = blockIdx.x * 256 + threadIdx.x;
    if (e >= D4) return;
    float4 v;
    v.x = src[e];
    v.y = src[D4 + e];
    v.z = src[2 * D4 + e];
    v.w = (n_ch == 4) ? src[3 * D4 + e] : 0.f;
    dst[e] = v;
}

__global__ __launch_bounds__(256) void fused_mlp(const float* __restrict__ vi,
                                                 const float* __restrict__ ir,
                                                 const float4* __restrict__ luts,
                                                 float* __restrict__ out) {
#pragma clang fp contract(off)
    int p = blockIdx.x * 256 + threadIdx.x;
    if (p >= NPIX) return;
    int b  = p >> 18;
    int hw = p & (HW - 1);
    int vbase = (b * 3) << 18;

    float x0 = vi[vbase + hw];
    float x1 = vi[vbase + HW + hw];
    float x2 = vi[vbase + 2 * HW + hw];
    float x3 = ir[p];

    for (int s = 0; s < 6; ++s) {
        const float4* __restrict__ lut = luts + (size_t)s * D4;
        x0 = fminf(fmaxf(x0, 0.f), 1.f);
        x1 = fminf(fmaxf(x1, 0.f), 1.f);
        x2 = fminf(fmaxf(x2, 0.f), 1.f);
        x3 = fminf(fmaxf(x3, 0.f), 1.f);
        float xs0 = x0 * 16.f;
        float xs1 = x1 * 16.f;
        float xs2 = x2 * 16.f;
        float xs3 = x3 * 16.f;
        int i0 = (int)xs0; i0 = i0 > 15 ? 15 : i0;
        int i1 = (int)xs1; i1 = i1 > 15 ? 15 : i1;
        int i2 = (int)xs2; i2 = i2 > 15 ? 15 : i2;
        int i3 = (int)xs3; i3 = i3 > 15 ? 15 : i3;
        float f0 = xs0 - (float)i0;
        float f1 = xs1 - (float)i1;
        float f2 = xs2 - (float)i2;
        float f3 = xs3 - (float)i3;
        float g0 = 1.f - f0;
        float g1 = 1.f - f1;
        float g2 = 1.f - f2;
        float g3 = 1.f - f3;
        float w01[4] = { g0 * g1, f0 * g1, g0 * f1, f0 * f1 };
        int off = i0 * 4913 + i1 * 289 + i2 * 17 + i3;

        float4 v[16];
#pragma unroll
        for (int hi = 0; hi < 2; ++hi) {
#pragma unroll
            for (int c = 0; c < 8; ++c) {
                int d = (c & 1) * 4913 + ((c >> 1) & 1) * 289 + (c >> 2) * 17 + hi;
                v[hi * 8 + c] = lut[off + d];
            }
        }
        __builtin_amdgcn_sched_barrier(0);

        float a0 = 0.f, a1 = 0.f, a2 = 0.f, a3 = 0.f;
#pragma unroll
        for (int hi = 0; hi < 2; ++hi) {
            float w3 = hi ? f3 : g3;
#pragma unroll
            for (int c = 0; c < 8; ++c) {
                float4 vv = v[hi * 8 + c];
                float w012 = w01[c & 3] * ((c >> 2) ? f2 : g2);
                float w    = w012 * w3;
                if (hi == 0 && c == 0) {
                    a0 = vv.x * w; a1 = vv.y * w; a2 = vv.z * w; a3 = vv.w * w;
                } else {
                    a0 = a0 + vv.x * w; a1 = a1 + vv.y * w;
                    a2 = a2 + vv.z * w; a3 = a3 + vv.w * w;
                }
            }
        }
        x0 = a0; x1 = a1; x2 = a2; x3 = a3;
    }

    out[vbase + hw]          = x0;
    out[vbase + HW + hw]     = x1;
    out[vbase + 2 * HW + hw] = x2;
}

// ---------- raw fallback (no workspace) -------------------------------------
__global__ __launch_bounds__(256) void fused_fallback(const float* __restrict__ vi,
                                                      const float* __restrict__ ir,
                                                      const float* __restrict__ l8,
                                                      const float* __restrict__ l00,
                                                      const float* __restrict__ l01,
                                                      const float* __restrict__ l02,
                                                      const float* __restrict__ l03,
                                                      const float* __restrict__ lpgf,
                                                      float* __restrict__ out) {
#pragma clang fp contract(off)
    int p = blockIdx.x * 256 + threadIdx.x;
    if (p >= NPIX) return;
    int b  = p >> 18;
    int hw = p & (HW - 1);
    int vbase = (b * 3) << 18;

    const float* ptrs[6] = { l8, l00, l01, l02, l03, lpgf };

    float x0 = vi[vbase + hw];
    float x1 = vi[vbase + HW + hw];
    float x2 = vi[vbase + 2 * HW + hw];
    float x3 = ir[p];

    for (int s = 0; s < 6; ++s) {
        const float* __restrict__ L = ptrs[s];
        int n_ch = (s == 5) ? 3 : 4;
        x0 = fminf(fmaxf(x0, 0.f), 1.f);
        x1 = fminf(fmaxf(x1, 0.f), 1.f);
        x2 = fminf(fmaxf(x2, 0.f), 1.f);
        x3 = fminf(fmaxf(x3, 0.f), 1.f);
        float xs0 = x0 * 16.f;
        float xs1 = x1 * 16.f;
        float xs2 = x2 * 16.f;
        float xs3 = x3 * 16.f;
        int i0 = (int)xs0; i0 = i0 > 15 ? 15 : i0;
        int i1 = (int)xs1; i1 = i1 > 15 ? 15 : i1;
        int i2 = (int)xs2; i2 = i2 > 15 ? 15 : i2;
        int i3 = (int)xs3; i3 = i3 > 15 ? 15 : i3;
        float f0 = xs0 - (float)i0;
        float f1 = xs1 - (float)i1;
        float f2 = xs2 - (float)i2;
        float f3 = xs3 - (float)i3;
        float g0 = 1.f - f0;
        float g1 = 1.f - f1;
        float g2 = 1.f - f2;
        float g3 = 1.f - f3;
        float w01[4] = { g0 * g1, f0 * g1, g0 * f1, f0 * f1 };
        int off = i0 * 4913 + i1 * 289 + i2 * 17 + i3;
        float a0 = 0.f, a1 = 0.f, a2 = 0.f, a3 = 0.f;
        for (int cr = 0; cr < 16; ++cr) {
            int hi = cr >> 3, c = cr & 7;
            int idx = off + (c & 1) * 4913 + ((c >> 1) & 1) * 289 + (c >> 2) * 17 + hi;
            float w012 = w01[c & 3] * ((c >> 2) ? f2 : g2);
            float w    = w012 * (hi ? f3 : g3);
            float v0 = L[idx];
            float v1 = L[D4 + idx];
            float v2 = L[2 * D4 + idx];
            float v3 = (n_ch == 4) ? L[3 * D4 + idx] : 0.f;
            if (cr == 0) {
                a0 = v0 * w; a1 = v1 * w; a2 = v2 * w; a3 = v3 * w;
            } else {
                a0 = a0 + v0 * w; a1 = a1 + v1 * w;
                a2 = a2 + v2 * w; a3 = a3 + v3 * w;
            }
        }
        x0 = a0; x1 = a1; x2 = a2; x3 = a3;
    }

    out[vbase + hw]          = x0;
    out[vbase + HW + hw]     = x1;
    out[vbase + 2 * HW + hw] = x2;
}

extern "C" void kernel_launch(void* const* d_in, const int* in_sizes, int n_in,
                              void* d_out, int out_size, void* d_ws, size_t ws_size,
                              hipStream_t stream) {
    const float* vi = (const float*)d_in[0];
    const float* ir = (const float*)d_in[1];
    const float* raw[6] = {
        (const float*)d_in[2], (const float*)d_in[3],
        (const float*)d_in[4], (const float*)d_in[5],
        (const float*)d_in[6], (const float*)d_in[7]
    };
    float* out = (float*)d_out;

    const size_t QSZ      = (size_t)QREC * 64;            // 4,734,976 B per LUT
    const size_t COORD_OFF= 6 * QSZ;                      // 28,409,856 (256-mult)
    const size_t NEED_Q   = COORD_OFF + (size_t)NPIX * 16; // ~59.1 MB
    const size_t NEED_LIN = (size_t)6 * D4 * sizeof(float4); // ~8.0 MB

    if (ws_size >= NEED_Q) {
        char* ws = (char*)d_ws;
        float4* coords = (float4*)(ws + COORD_OFF);
        int pack_blocks = (QREC + 255) / 256;
        for (int s = 0; s < 6; ++s) {
            pack_quad<<<pack_blocks, 256, 0, stream>>>(raw[s], (s == 5) ? 3 : 4,
                                                       (float4*)(ws + s * QSZ));
        }
        int g = NPIX / 256;
        k_stage_first<<<g, 256, 0, stream>>>(vi, ir, (const float4*)ws, coords);
        for (int s = 1; s <= 4; ++s) {
            k_stage_mid<<<g, 256, 0, stream>>>(coords,
                                               (const float4*)(ws + s * QSZ));
        }
        k_stage_last<<<g, 256, 0, stream>>>(coords,
                                            (const float4*)(ws + 5 * QSZ), out);
    } else if (ws_size >= NEED_LIN) {
        float4* packed = (float4*)d_ws;
        int pack_blocks = (D4 + 255) / 256;
        for (int s = 0; s < 6; ++s) {
            pack_kernel<<<pack_blocks, 256, 0, stream>>>(raw[s], (s == 5) ? 3 : 4,
                                                         packed + (size_t)s * D4);
        }
        fused_mlp<<<NPIX / 256, 256, 0, stream>>>(vi, ir, packed, out);
    } else {
        fused_fallback<<<NPIX / 256, 256, 0, stream>>>(vi, ir, raw[0], raw[1], raw[2],
                                                       raw[3], raw[4], raw[5], out);
    }
}

// Round 12
// 384.300 us; speedup vs baseline: 17.2204x; 1.8297x over previous
//
#include <hip/hip_runtime.h>

// CRITICAL: bit-exact replication of the numpy fp32 oracle requires NO FMA
// contraction (hipcc default -ffp-contract=fast-honor-pragmas would fuse).
#pragma clang fp contract(off)

#define D4    83521      // 17^4 entries per LUT (per channel)
#define HW    262144     // 512*512
#define NPIX  2097152    // 8*512*512
#define QREC  73984      // 17*17*16*16 quad records per LUT (64 B each)
#define BLK   128        // threads per block for the cooperative kernel

// ---------- quad packing: one 64 B record = 2x2 (i2,i3) corner block --------
// Record r = ((i0*17 + i1)*16 + i2)*16 + i3 (i2,i3 in [0,16)); slot g holds
// channels of corner (i2+(g&1), i3+(g>>1)). Verified bit-exact (rounds 7/11).
__global__ __launch_bounds__(256) void pack_quad(const float* __restrict__ src,
                                                 int n_ch,
                                                 float4* __restrict__ dst) {
    int e = blockIdx.x * 256 + threadIdx.x;
    if (e >= QREC) return;
    int i3 = e & 15;
    int i2 = (e >> 4) & 15;
    int t  = e >> 8;              // i0*17 + i1
    int i0 = t / 17;
    int i1 = t - i0 * 17;
    int base = i0 * 4913 + i1 * 289 + i2 * 17 + i3;
    float4* rec = dst + (size_t)e * 4;
#pragma unroll
    for (int g = 0; g < 4; ++g) {
        int o = base + (g & 1) * 17 + (g >> 1);
        float4 v;
        v.x = src[o];
        v.y = src[D4 + o];
        v.z = src[2 * D4 + o];
        v.w = (n_ch == 4) ? src[3 * D4 + o] : 0.f;
        rec[g] = v;
    }
}

// Cooperative fused 6-stage chain.
// Ownership: thread tid owns pixel blockIdx*BLK + tid for the whole chain.
// Gather phase per stage: 16 lanes cooperate per pixel — lane l of a wave
// loads record rec=(l>>2)&3, slot=l&3 for pixel (wavebase + 4t + (l>>4)),
// t=0..15. Lane-quads hit consecutive 16 B of one 64 B record -> 1 coalesced
// transaction (4 transactions/px-stage vs 16 in thread-per-pixel form).
// Fragments are exchanged via LDS (bit-preserving), then each owner runs the
// VERBATIM round-6 sequential accumulation -> bit-exact by construction.
// NOTE: no early-return guard — NPIX % BLK == 0, barriers are uniform.
__global__ __launch_bounds__(BLK) void fused_coop(const float* __restrict__ vi,
                                                  const float* __restrict__ ir,
                                                  const float4* __restrict__ luts,
                                                  float* __restrict__ out) {
#pragma clang fp contract(off)
    __shared__ float4 exch[BLK * 17];   // 272 B per pixel (17 float4, bank-rotating)
    __shared__ int    r00buf[BLK];

    int tid   = threadIdx.x;
    int lane  = tid & 63;
    int wbase = tid & 64;               // this wave's pixel base within block
    int p = blockIdx.x * BLK + tid;
    int b  = p >> 18;                   // HW = 2^18
    int hw = p & (HW - 1);
    int vbase = (b * 3) << 18;

    float x0 = vi[vbase + hw];
    float x1 = vi[vbase + HW + hw];
    float x2 = vi[vbase + 2 * HW + hw];
    float x3 = ir[p];

    int rec     = (lane >> 2) & 3;      // loader role, fixed per lane
    int slot    = lane & 3;
    int rec_off = ((rec & 1) ? 4352 : 0) + ((rec & 2) ? 256 : 0);
    int sub     = lane >> 4;            // which pixel of each 4-px group
    int kidx    = lane & 15;            // rec*4 + slot

    for (int s = 0; s < 6; ++s) {
        const float4* __restrict__ lut = luts + (size_t)s * QREC * 4;

        // ---- owner: indices + weights (exact round-6 arithmetic) ----
        x0 = fminf(fmaxf(x0, 0.f), 1.f);
        x1 = fminf(fmaxf(x1, 0.f), 1.f);
        x2 = fminf(fmaxf(x2, 0.f), 1.f);
        x3 = fminf(fmaxf(x3, 0.f), 1.f);
        float xs0 = x0 * 16.f;
        float xs1 = x1 * 16.f;
        float xs2 = x2 * 16.f;
        float xs3 = x3 * 16.f;
        int i0 = (int)xs0; i0 = i0 > 15 ? 15 : i0;
        int i1 = (int)xs1; i1 = i1 > 15 ? 15 : i1;
        int i2 = (int)xs2; i2 = i2 > 15 ? 15 : i2;
        int i3 = (int)xs3; i3 = i3 > 15 ? 15 : i3;
        float f0 = xs0 - (float)i0;     // mul-then-sub, contraction OFF
        float f1 = xs1 - (float)i1;
        float f2 = xs2 - (float)i2;
        float f3 = xs3 - (float)i3;
        float g0 = 1.f - f0;
        float g1 = 1.f - f1;
        float g2 = 1.f - f2;
        float g3 = 1.f - f3;
        float w01[4] = { g0 * g1, f0 * g1, g0 * f1, f0 * f1 };

        r00buf[tid] = ((i0 * 17 + i1) * 16 + i2) * 16 + i3;
        __syncthreads();                // r00 visible; prev-stage exch reads done

        // ---- cooperative gather: 16 loads/lane, 16 coalesced trans/instr ----
        int r0s[16];
#pragma unroll
        for (int t = 0; t < 16; ++t)
            r0s[t] = r00buf[wbase + 4 * t + sub];
        float4 v[16];
#pragma unroll
        for (int t = 0; t < 16; ++t)
            v[t] = lut[(size_t)(r0s[t] + rec_off) * 4 + slot];
        __builtin_amdgcn_sched_barrier(0);   // keep the 16-deep load batch intact
#pragma unroll
        for (int t = 0; t < 16; ++t)
            exch[(wbase + 4 * t + sub) * 17 + kidx] = v[t];
        __syncthreads();                // all fragments landed

        // ---- owner: exact round-6 sequential accumulation ----
        const float4* myb = &exch[tid * 17];
        float a0 = 0.f, a1 = 0.f, a2 = 0.f, a3 = 0.f;
#pragma unroll
        for (int hi = 0; hi < 2; ++hi) {     // b3
            float w3 = hi ? f3 : g3;
#pragma unroll
            for (int c = 0; c < 8; ++c) {    // b0=c&1, b1=(c>>1)&1, b2=c>>2
                int k = ((c & 3) << 2) + ((c >> 2) + 2 * hi);  // rec*4 + slot
                float4 vv = myb[k];
                float w012 = w01[c & 3] * ((c >> 2) ? f2 : g2);
                float w    = w012 * w3;
                if (hi == 0 && c == 0) {
                    a0 = vv.x * w; a1 = vv.y * w; a2 = vv.z * w; a3 = vv.w * w;
                } else {
                    a0 = a0 + vv.x * w; a1 = a1 + vv.y * w;
                    a2 = a2 + vv.z * w; a3 = a3 + vv.w * w;
                }
            }
        }
        x0 = a0; x1 = a1; x2 = a2; x3 = a3;
    }

    out[vbase + hw]          = x0;
    out[vbase + HW + hw]     = x1;
    out[vbase + 2 * HW + hw] = x2;
}

// ---------- middle tier: round-10 fused kernel (proven, 653 us) -------------
__global__ __launch_bounds__(256) void pack_kernel(const float* __restrict__ src,
                                                   int n_ch,
                                                   float4* __restrict__ dst) {
    int e = blockIdx.x * 256 + threadIdx.x;
    if (e >= D4) return;
    float4 v;
    v.x = src[e];
    v.y = src[D4 + e];
    v.z = src[2 * D4 + e];
    v.w = (n_ch == 4) ? src[3 * D4 + e] : 0.f;
    dst[e] = v;
}

__global__ __launch_bounds__(256) void fused_mlp(const float* __restrict__ vi,
                                                 const float* __restrict__ ir,
                                                 const float4* __restrict__ luts,
                                                 float* __restrict__ out) {
#pragma clang fp contract(off)
    int p = blockIdx.x * 256 + threadIdx.x;
    if (p >= NPIX) return;
    int b  = p >> 18;
    int hw = p & (HW - 1);
    int vbase = (b * 3) << 18;

    float x0 = vi[vbase + hw];
    float x1 = vi[vbase + HW + hw];
    float x2 = vi[vbase + 2 * HW + hw];
    float x3 = ir[p];

    for (int s = 0; s < 6; ++s) {
        const float4* __restrict__ lut = luts + (size_t)s * D4;
        x0 = fminf(fmaxf(x0, 0.f), 1.f);
        x1 = fminf(fmaxf(x1, 0.f), 1.f);
        x2 = fminf(fmaxf(x2, 0.f), 1.f);
        x3 = fminf(fmaxf(x3, 0.f), 1.f);
        float xs0 = x0 * 16.f;
        float xs1 = x1 * 16.f;
        float xs2 = x2 * 16.f;
        float xs3 = x3 * 16.f;
        int i0 = (int)xs0; i0 = i0 > 15 ? 15 : i0;
        int i1 = (int)xs1; i1 = i1 > 15 ? 15 : i1;
        int i2 = (int)xs2; i2 = i2 > 15 ? 15 : i2;
        int i3 = (int)xs3; i3 = i3 > 15 ? 15 : i3;
        float f0 = xs0 - (float)i0;
        float f1 = xs1 - (float)i1;
        float f2 = xs2 - (float)i2;
        float f3 = xs3 - (float)i3;
        float g0 = 1.f - f0;
        float g1 = 1.f - f1;
        float g2 = 1.f - f2;
        float g3 = 1.f - f3;
        float w01[4] = { g0 * g1, f0 * g1, g0 * f1, f0 * f1 };
        int off = i0 * 4913 + i1 * 289 + i2 * 17 + i3;

        float4 v[16];
#pragma unroll
        for (int hi = 0; hi < 2; ++hi) {
#pragma unroll
            for (int c = 0; c < 8; ++c) {
                int d = (c & 1) * 4913 + ((c >> 1) & 1) * 289 + (c >> 2) * 17 + hi;
                v[hi * 8 + c] = lut[off + d];
            }
        }
        __builtin_amdgcn_sched_barrier(0);

        float a0 = 0.f, a1 = 0.f, a2 = 0.f, a3 = 0.f;
#pragma unroll
        for (int hi = 0; hi < 2; ++hi) {
            float w3 = hi ? f3 : g3;
#pragma unroll
            for (int c = 0; c < 8; ++c) {
                float4 vv = v[hi * 8 + c];
                float w012 = w01[c & 3] * ((c >> 2) ? f2 : g2);
                float w    = w012 * w3;
                if (hi == 0 && c == 0) {
                    a0 = vv.x * w; a1 = vv.y * w; a2 = vv.z * w; a3 = vv.w * w;
                } else {
                    a0 = a0 + vv.x * w; a1 = a1 + vv.y * w;
                    a2 = a2 + vv.z * w; a3 = a3 + vv.w * w;
                }
            }
        }
        x0 = a0; x1 = a1; x2 = a2; x3 = a3;
    }

    out[vbase + hw]          = x0;
    out[vbase + HW + hw]     = x1;
    out[vbase + 2 * HW + hw] = x2;
}

// ---------- raw fallback (no workspace) -------------------------------------
__global__ __launch_bounds__(256) void fused_fallback(const float* __restrict__ vi,
                                                      const float* __restrict__ ir,
                                                      const float* __restrict__ l8,
                                                      const float* __restrict__ l00,
                                                      const float* __restrict__ l01,
                                                      const float* __restrict__ l02,
                                                      const float* __restrict__ l03,
                                                      const float* __restrict__ lpgf,
                                                      float* __restrict__ out) {
#pragma clang fp contract(off)
    int p = blockIdx.x * 256 + threadIdx.x;
    if (p >= NPIX) return;
    int b  = p >> 18;
    int hw = p & (HW - 1);
    int vbase = (b * 3) << 18;

    const float* ptrs[6] = { l8, l00, l01, l02, l03, lpgf };

    float x0 = vi[vbase + hw];
    float x1 = vi[vbase + HW + hw];
    float x2 = vi[vbase + 2 * HW + hw];
    float x3 = ir[p];

    for (int s = 0; s < 6; ++s) {
        const float* __restrict__ L = ptrs[s];
        int n_ch = (s == 5) ? 3 : 4;
        x0 = fminf(fmaxf(x0, 0.f), 1.f);
        x1 = fminf(fmaxf(x1, 0.f), 1.f);
        x2 = fminf(fmaxf(x2, 0.f), 1.f);
        x3 = fminf(fmaxf(x3, 0.f), 1.f);
        float xs0 = x0 * 16.f;
        float xs1 = x1 * 16.f;
        float xs2 = x2 * 16.f;
        float xs3 = x3 * 16.f;
        int i0 = (int)xs0; i0 = i0 > 15 ? 15 : i0;
        int i1 = (int)xs1; i1 = i1 > 15 ? 15 : i1;
        int i2 = (int)xs2; i2 = i2 > 15 ? 15 : i2;
        int i3 = (int)xs3; i3 = i3 > 15 ? 15 : i3;
        float f0 = xs0 - (float)i0;
        float f1 = xs1 - (float)i1;
        float f2 = xs2 - (float)i2;
        float f3 = xs3 - (float)i3;
        float g0 = 1.f - f0;
        float g1 = 1.f - f1;
        float g2 = 1.f - f2;
        float g3 = 1.f - f3;
        float w01[4] = { g0 * g1, f0 * g1, g0 * f1, f0 * f1 };
        int off = i0 * 4913 + i1 * 289 + i2 * 17 + i3;
        float a0 = 0.f, a1 = 0.f, a2 = 0.f, a3 = 0.f;
        for (int cr = 0; cr < 16; ++cr) {
            int hi = cr >> 3, c = cr & 7;
            int idx = off + (c & 1) * 4913 + ((c >> 1) & 1) * 289 + (c >> 2) * 17 + hi;
            float w012 = w01[c & 3] * ((c >> 2) ? f2 : g2);
            float w    = w012 * (hi ? f3 : g3);
            float v0 = L[idx];
            float v1 = L[D4 + idx];
            float v2 = L[2 * D4 + idx];
            float v3 = (n_ch == 4) ? L[3 * D4 + idx] : 0.f;
            if (cr == 0) {
                a0 = v0 * w; a1 = v1 * w; a2 = v2 * w; a3 = v3 * w;
            } else {
                a0 = a0 + v0 * w; a1 = a1 + v1 * w;
                a2 = a2 + v2 * w; a3 = a3 + v3 * w;
            }
        }
        x0 = a0; x1 = a1; x2 = a2; x3 = a3;
    }

    out[vbase + hw]          = x0;
    out[vbase + HW + hw]     = x1;
    out[vbase + 2 * HW + hw] = x2;
}

extern "C" void kernel_launch(void* const* d_in, const int* in_sizes, int n_in,
                              void* d_out, int out_size, void* d_ws, size_t ws_size,
                              hipStream_t stream) {
    const float* vi = (const float*)d_in[0];
    const float* ir = (const float*)d_in[1];
    const float* raw[6] = {
        (const float*)d_in[2], (const float*)d_in[3],
        (const float*)d_in[4], (const float*)d_in[5],
        (const float*)d_in[6], (const float*)d_in[7]
    };
    float* out = (float*)d_out;

    const size_t QSZ      = (size_t)QREC * 64;               // 4,734,976 B/LUT
    const size_t NEED_Q   = 6 * QSZ;                         // ~28.4 MB
    const size_t NEED_LIN = (size_t)6 * D4 * sizeof(float4); // ~8.0 MB

    if (ws_size >= NEED_Q) {
        char* ws = (char*)d_ws;
        int pack_blocks = (QREC + 255) / 256;
        for (int s = 0; s < 6; ++s) {
            pack_quad<<<pack_blocks, 256, 0, stream>>>(raw[s], (s == 5) ? 3 : 4,
                                                       (float4*)(ws + s * QSZ));
        }
        fused_coop<<<NPIX / BLK, BLK, 0, stream>>>(vi, ir, (const float4*)ws, out);
    } else if (ws_size >= NEED_LIN) {
        float4* packed = (float4*)d_ws;
        int pack_blocks = (D4 + 255) / 256;
        for (int s = 0; s < 6; ++s) {
            pack_kernel<<<pack_blocks, 256, 0, stream>>>(raw[s], (s == 5) ? 3 : 4,
                                                         packed + (size_t)s * D4);
        }
        fused_mlp<<<NPIX / 256, 256, 0, stream>>>(vi, ir, packed, out);
    } else {
        fused_fallback<<<NPIX / 256, 256, 0, stream>>>(vi, ir, raw[0], raw[1], raw[2],
                                                       raw[3], raw[4], raw[5], out);
    }
}

// Round 13
// 384.004 us; speedup vs baseline: 17.2337x; 1.0008x over previous
//
#include <hip/hip_runtime.h>

// CRITICAL: bit-exact replication of the numpy fp32 oracle requires NO FMA
// contraction (hipcc default -ffp-contract=fast-honor-pragmas would fuse).
#pragma clang fp contract(off)

#define D4    83521      // 17^4 entries per LUT (per channel)
#define HW    262144     // 512*512
#define NPIX  2097152    // 8*512*512
#define QREC  73984      // 17*17*16*16 quad records per LUT (64 B each)
#define CBLK  64         // cooperative kernel: single-wave blocks

// ---------- quad packing: one 64 B record = 2x2 (i2,i3) corner block --------
// Record r = ((i0*17 + i1)*16 + i2)*16 + i3 (i2,i3 in [0,16)); slot g holds
// channels of corner (i2+(g&1), i3+(g>>1)). Verified bit-exact (r7/r11/r12).
__global__ __launch_bounds__(256) void pack_quad(const float* __restrict__ src,
                                                 int n_ch,
                                                 float4* __restrict__ dst) {
    int e = blockIdx.x * 256 + threadIdx.x;
    if (e >= QREC) return;
    int i3 = e & 15;
    int i2 = (e >> 4) & 15;
    int t  = e >> 8;              // i0*17 + i1
    int i0 = t / 17;
    int i1 = t - i0 * 17;
    int base = i0 * 4913 + i1 * 289 + i2 * 17 + i3;
    float4* rec = dst + (size_t)e * 4;
#pragma unroll
    for (int g = 0; g < 4; ++g) {
        int o = base + (g & 1) * 17 + (g >> 1);
        float4 v;
        v.x = src[o];
        v.y = src[D4 + o];
        v.z = src[2 * D4 + o];
        v.w = (n_ch == 4) ? src[3 * D4 + o] : 0.f;
        rec[g] = v;
    }
}

// Cooperative fused 6-stage chain — BARRIER-FREE (round 13).
// The r12 exchange is entirely within-wave (loader lane l serves pixels
// 4t+(l>>4), all in its own wave), so __syncthreads is unnecessary: DS ops
// execute in order per wave, and sched_barrier(0) pins program order of the
// write->read phases against compiler motion. r00 sharing via __shfl.
// Single-wave blocks: LDS 17.4 KB -> 9 blocks/CU, every wave free-runs.
// Arithmetic + exchange mapping verbatim r12 (bit-exact, absmax 0.0).
__global__ __launch_bounds__(CBLK) void fused_coop(const float* __restrict__ vi,
                                                   const float* __restrict__ ir,
                                                   const float4* __restrict__ luts,
                                                   float* __restrict__ out) {
#pragma clang fp contract(off)
    __shared__ float4 exch[CBLK * 17];  // 272 B per pixel (17-float4 rows, conflict-free)

    int tid = threadIdx.x;              // == lane (single-wave block)
    int p = blockIdx.x * CBLK + tid;
    int b  = p >> 18;                   // HW = 2^18
    int hw = p & (HW - 1);
    int vbase = (b * 3) << 18;

    float x0 = vi[vbase + hw];
    float x1 = vi[vbase + HW + hw];
    float x2 = vi[vbase + 2 * HW + hw];
    float x3 = ir[p];

    int rec     = (tid >> 2) & 3;       // loader role, fixed per lane
    int slot    = tid & 3;
    int rec_off = ((rec & 1) ? 4352 : 0) + ((rec & 2) ? 256 : 0);
    int sub     = tid >> 4;             // which pixel of each 4-px group
    int kidx    = tid & 15;             // rec*4 + slot

    for (int s = 0; s < 6; ++s) {
        // per-lane LUT base folds in the role offset (addr calc once)
        const float4* __restrict__ lutS =
            luts + (size_t)s * QREC * 4 + (size_t)rec_off * 4 + slot;

        // ---- owner: indices + weights (exact round-6 arithmetic) ----
        x0 = fminf(fmaxf(x0, 0.f), 1.f);
        x1 = fminf(fmaxf(x1, 0.f), 1.f);
        x2 = fminf(fmaxf(x2, 0.f), 1.f);
        x3 = fminf(fmaxf(x3, 0.f), 1.f);
        float xs0 = x0 * 16.f;
        float xs1 = x1 * 16.f;
        float xs2 = x2 * 16.f;
        float xs3 = x3 * 16.f;
        int i0 = (int)xs0; i0 = i0 > 15 ? 15 : i0;
        int i1 = (int)xs1; i1 = i1 > 15 ? 15 : i1;
        int i2 = (int)xs2; i2 = i2 > 15 ? 15 : i2;
        int i3 = (int)xs3; i3 = i3 > 15 ? 15 : i3;
        float f0 = xs0 - (float)i0;     // mul-then-sub, contraction OFF
        float f1 = xs1 - (float)i1;
        float f2 = xs2 - (float)i2;
        float f3 = xs3 - (float)i3;
        float g0 = 1.f - f0;
        float g1 = 1.f - f1;
        float g2 = 1.f - f2;
        float g3 = 1.f - f3;
        float w01[4] = { g0 * g1, f0 * g1, g0 * f1, f0 * f1 };

        int r00 = ((i0 * 17 + i1) * 16 + i2) * 16 + i3;

        // ---- r00 exchange: pure in-wave shuffle, no LDS / no barrier ----
        int r0s[16];
#pragma unroll
        for (int t = 0; t < 16; ++t)
            r0s[t] = __shfl(r00, 4 * t + sub, 64);

        // ---- cooperative gather: 16 loads/lane, 16 coalesced trans/instr ----
        float4 v[16];
#pragma unroll
        for (int t = 0; t < 16; ++t)
            v[t] = lutS[(size_t)r0s[t] * 4];
        __builtin_amdgcn_sched_barrier(0);   // keep the 16-deep load batch intact

        // ---- in-wave fragment exchange (DS ops in order per wave) ----
#pragma unroll
        for (int t = 0; t < 16; ++t)
            exch[(4 * t + sub) * 17 + kidx] = v[t];
        __builtin_amdgcn_sched_barrier(0);   // pin write->read program order

        // ---- owner: exact round-6 sequential accumulation ----
        const float4* myb = &exch[tid * 17];
        float a0 = 0.f, a1 = 0.f, a2 = 0.f, a3 = 0.f;
#pragma unroll
        for (int hi = 0; hi < 2; ++hi) {     // b3
            float w3 = hi ? f3 : g3;
#pragma unroll
            for (int c = 0; c < 8; ++c) {    // b0=c&1, b1=(c>>1)&1, b2=c>>2
                int k = ((c & 3) << 2) + ((c >> 2) + 2 * hi);  // rec*4 + slot
                float4 vv = myb[k];
                float w012 = w01[c & 3] * ((c >> 2) ? f2 : g2);
                float w    = w012 * w3;
                if (hi == 0 && c == 0) {
                    a0 = vv.x * w; a1 = vv.y * w; a2 = vv.z * w; a3 = vv.w * w;
                } else {
                    a0 = a0 + vv.x * w; a1 = a1 + vv.y * w;
                    a2 = a2 + vv.z * w; a3 = a3 + vv.w * w;
                }
            }
        }
        __builtin_amdgcn_sched_barrier(0);   // reads done before next stage's writes
        x0 = a0; x1 = a1; x2 = a2; x3 = a3;
    }

    out[vbase + hw]          = x0;
    out[vbase + HW + hw]     = x1;
    out[vbase + 2 * HW + hw] = x2;
}

// ---------- middle tier: round-10 fused kernel (proven, 653 us) -------------
__global__ __launch_bounds__(256) void pack_kernel(const float* __restrict__ src,
                                                   int n_ch,
                                                   float4* __restrict__ dst) {
    int e = blockIdx.x * 256 + threadIdx.x;
    if (e >= D4) return;
    float4 v;
    v.x = src[e];
    v.y = src[D4 + e];
    v.z = src[2 * D4 + e];
    v.w = (n_ch == 4) ? src[3 * D4 + e] : 0.f;
    dst[e] = v;
}

__global__ __launch_bounds__(256) void fused_mlp(const float* __restrict__ vi,
                                                 const float* __restrict__ ir,
                                                 const float4* __restrict__ luts,
                                                 float* __restrict__ out) {
#pragma clang fp contract(off)
    int p = blockIdx.x * 256 + threadIdx.x;
    if (p >= NPIX) return;
    int b  = p >> 18;
    int hw = p & (HW - 1);
    int vbase = (b * 3) << 18;

    float x0 = vi[vbase + hw];
    float x1 = vi[vbase + HW + hw];
    float x2 = vi[vbase + 2 * HW + hw];
    float x3 = ir[p];

    for (int s = 0; s < 6; ++s) {
        const float4* __restrict__ lut = luts + (size_t)s * D4;
        x0 = fminf(fmaxf(x0, 0.f), 1.f);
        x1 = fminf(fmaxf(x1, 0.f), 1.f);
        x2 = fminf(fmaxf(x2, 0.f), 1.f);
        x3 = fminf(fmaxf(x3, 0.f), 1.f);
        float xs0 = x0 * 16.f;
        float xs1 = x1 * 16.f;
        float xs2 = x2 * 16.f;
        float xs3 = x3 * 16.f;
        int i0 = (int)xs0; i0 = i0 > 15 ? 15 : i0;
        int i1 = (int)xs1; i1 = i1 > 15 ? 15 : i1;
        int i2 = (int)xs2; i2 = i2 > 15 ? 15 : i2;
        int i3 = (int)xs3; i3 = i3 > 15 ? 15 : i3;
        float f0 = xs0 - (float)i0;
        float f1 = xs1 - (float)i1;
        float f2 = xs2 - (float)i2;
        float f3 = xs3 - (float)i3;
        float g0 = 1.f - f0;
        float g1 = 1.f - f1;
        float g2 = 1.f - f2;
        float g3 = 1.f - f3;
        float w01[4] = { g0 * g1, f0 * g1, g0 * f1, f0 * f1 };
        int off = i0 * 4913 + i1 * 289 + i2 * 17 + i3;

        float4 v[16];
#pragma unroll
        for (int hi = 0; hi < 2; ++hi) {
#pragma unroll
            for (int c = 0; c < 8; ++c) {
                int d = (c & 1) * 4913 + ((c >> 1) & 1) * 289 + (c >> 2) * 17 + hi;
                v[hi * 8 + c] = lut[off + d];
            }
        }
        __builtin_amdgcn_sched_barrier(0);

        float a0 = 0.f, a1 = 0.f, a2 = 0.f, a3 = 0.f;
#pragma unroll
        for (int hi = 0; hi < 2; ++hi) {
            float w3 = hi ? f3 : g3;
#pragma unroll
            for (int c = 0; c < 8; ++c) {
                float4 vv = v[hi * 8 + c];
                float w012 = w01[c & 3] * ((c >> 2) ? f2 : g2);
                float w    = w012 * w3;
                if (hi == 0 && c == 0) {
                    a0 = vv.x * w; a1 = vv.y * w; a2 = vv.z * w; a3 = vv.w * w;
                } else {
                    a0 = a0 + vv.x * w; a1 = a1 + vv.y * w;
                    a2 = a2 + vv.z * w; a3 = a3 + vv.w * w;
                }
            }
        }
        x0 = a0; x1 = a1; x2 = a2; x3 = a3;
    }

    out[vbase + hw]          = x0;
    out[vbase + HW + hw]     = x1;
    out[vbase + 2 * HW + hw] = x2;
}

// ---------- raw fallback (no workspace) -------------------------------------
__global__ __launch_bounds__(256) void fused_fallback(const float* __restrict__ vi,
                                                      const float* __restrict__ ir,
                                                      const float* __restrict__ l8,
                                                      const float* __restrict__ l00,
                                                      const float* __restrict__ l01,
                                                      const float* __restrict__ l02,
                                                      const float* __restrict__ l03,
                                                      const float* __restrict__ lpgf,
                                                      float* __restrict__ out) {
#pragma clang fp contract(off)
    int p = blockIdx.x * 256 + threadIdx.x;
    if (p >= NPIX) return;
    int b  = p >> 18;
    int hw = p & (HW - 1);
    int vbase = (b * 3) << 18;

    const float* ptrs[6] = { l8, l00, l01, l02, l03, lpgf };

    float x0 = vi[vbase + hw];
    float x1 = vi[vbase + HW + hw];
    float x2 = vi[vbase + 2 * HW + hw];
    float x3 = ir[p];

    for (int s = 0; s < 6; ++s) {
        const float* __restrict__ L = ptrs[s];
        int n_ch = (s == 5) ? 3 : 4;
        x0 = fminf(fmaxf(x0, 0.f), 1.f);
        x1 = fminf(fmaxf(x1, 0.f), 1.f);
        x2 = fminf(fmaxf(x2, 0.f), 1.f);
        x3 = fminf(fmaxf(x3, 0.f), 1.f);
        float xs0 = x0 * 16.f;
        float xs1 = x1 * 16.f;
        float xs2 = x2 * 16.f;
        float xs3 = x3 * 16.f;
        int i0 = (int)xs0; i0 = i0 > 15 ? 15 : i0;
        int i1 = (int)xs1; i1 = i1 > 15 ? 15 : i1;
        int i2 = (int)xs2; i2 = i2 > 15 ? 15 : i2;
        int i3 = (int)xs3; i3 = i3 > 15 ? 15 : i3;
        float f0 = xs0 - (float)i0;
        float f1 = xs1 - (float)i1;
        float f2 = xs2 - (float)i2;
        float f3 = xs3 - (float)i3;
        float g0 = 1.f - f0;
        float g1 = 1.f - f1;
        float g2 = 1.f - f2;
        float g3 = 1.f - f3;
        float w01[4] = { g0 * g1, f0 * g1, g0 * f1, f0 * f1 };
        int off = i0 * 4913 + i1 * 289 + i2 * 17 + i3;
        float a0 = 0.f, a1 = 0.f, a2 = 0.f, a3 = 0.f;
        for (int cr = 0; cr < 16; ++cr) {
            int hi = cr >> 3, c = cr & 7;
            int idx = off + (c & 1) * 4913 + ((c >> 1) & 1) * 289 + (c >> 2) * 17 + hi;
            float w012 = w01[c & 3] * ((c >> 2) ? f2 : g2);
            float w    = w012 * (hi ? f3 : g3);
            float v0 = L[idx];
            float v1 = L[D4 + idx];
            float v2 = L[2 * D4 + idx];
            float v3 = (n_ch == 4) ? L[3 * D4 + idx] : 0.f;
            if (cr == 0) {
                a0 = v0 * w; a1 = v1 * w; a2 = v2 * w; a3 = v3 * w;
            } else {
                a0 = a0 + v0 * w; a1 = a1 + v1 * w;
                a2 = a2 + v2 * w; a3 = a3 + v3 * w;
            }
        }
        x0 = a0; x1 = a1; x2 = a2; x3 = a3;
    }

    out[vbase + hw]          = x0;
    out[vbase + HW + hw]     = x1;
    out[vbase + 2 * HW + hw] = x2;
}

extern "C" void kernel_launch(void* const* d_in, const int* in_sizes, int n_in,
                              void* d_out, int out_size, void* d_ws, size_t ws_size,
                              hipStream_t stream) {
    const float* vi = (const float*)d_in[0];
    const float* ir = (const float*)d_in[1];
    const float* raw[6] = {
        (const float*)d_in[2], (const float*)d_in[3],
        (const float*)d_in[4], (const float*)d_in[5],
        (const float*)d_in[6], (const float*)d_in[7]
    };
    float* out = (float*)d_out;

    const size_t QSZ      = (size_t)QREC * 64;               // 4,734,976 B/LUT
    const size_t NEED_Q   = 6 * QSZ;                         // ~28.4 MB
    const size_t NEED_LIN = (size_t)6 * D4 * sizeof(float4); // ~8.0 MB

    if (ws_size >= NEED_Q) {
        char* ws = (char*)d_ws;
        int pack_blocks = (QREC + 255) / 256;
        for (int s = 0; s < 6; ++s) {
            pack_quad<<<pack_blocks, 256, 0, stream>>>(raw[s], (s == 5) ? 3 : 4,
                                                       (float4*)(ws + s * QSZ));
        }
        fused_coop<<<NPIX / CBLK, CBLK, 0, stream>>>(vi, ir, (const float4*)ws, out);
    } else if (ws_size >= NEED_LIN) {
        float4* packed = (float4*)d_ws;
        int pack_blocks = (D4 + 255) / 256;
        for (int s = 0; s < 6; ++s) {
            pack_kernel<<<pack_blocks, 256, 0, stream>>>(raw[s], (s == 5) ? 3 : 4,
                                                         packed + (size_t)s * D4);
        }
        fused_mlp<<<NPIX / 256, 256, 0, stream>>>(vi, ir, packed, out);
    } else {
        fused_fallback<<<NPIX / 256, 256, 0, stream>>>(vi, ir, raw[0], raw[1], raw[2],
                                                       raw[3], raw[4], raw[5], out);
    }
}